// Round 19
// baseline (13996.962 us; speedup 1.0000x reference)
//
#include <hip/hip_runtime.h>
#include <hip/hip_bf16.h>

// ---------------- constants ----------------
static constexpr int kT    = 2048;
static constexpr int kOUT_ELEMS = 2048 * 4096;   // output 0 size

typedef _Float16 half2_t __attribute__((ext_vector_type(2)));
typedef unsigned long long u64;

__device__ __forceinline__ unsigned pack_h2(float a, float b) {
  half2_t h{(_Float16)a, (_Float16)b};
  return __builtin_bit_cast(unsigned, h);
}
__device__ __forceinline__ float fdot2u(unsigned a, unsigned b, float c) {
  return __builtin_amdgcn_fdot2(__builtin_bit_cast(half2_t, a),
                                __builtin_bit_cast(half2_t, b), c, false);
}
__device__ __forceinline__ float sigm(float x) {
  return 1.f / (1.f + __expf(-x));
}
__device__ __forceinline__ float tanh_f(float x) {
  float ax = fabsf(x);
  float e = __expf(-2.f * ax);
  float r = (1.f - e) / (1.f + e);
  return x < 0.f ? -r : r;
}

// ---------------- K0: prep ----------------
// wprep5 [ld<4][p<4][e<128][r<256]: half2 col e of gate-row r_local (gate=r>>6, m=r&63,
//   R=gate*256+64p+m). wgru [g2<2][e<64][row<384]; payload tags zeroed each launch.
__global__ __launch_bounds__(256) void prep_kernel(
    const float* __restrict__ enc_Wih, const float* __restrict__ enc_bih,
    const float* __restrict__ cenc_Wih, const float* __restrict__ cenc_bih,
    const float* __restrict__ enc_Whh, const float* __restrict__ cenc_Whh,
    const float* __restrict__ l0_Whh, const float* __restrict__ l1_Whh,
    const float* __restrict__ l0_bih, const float* __restrict__ l0_bhh,
    const float* __restrict__ l1_bih, const float* __restrict__ l1_bhh,
    float* __restrict__ wcat, float* __restrict__ bcat,
    float* __restrict__ bias0, float* __restrict__ bias1,
    unsigned* __restrict__ wprep5, unsigned* __restrict__ wgru,
    u64* __restrict__ payz) {
  int idx0 = blockIdx.x * blockDim.x + threadIdx.x;
  int stride = gridDim.x * blockDim.x;
  for (int i = idx0; i < 1024; i += stride) payz[i] = 0ull;   // re-zero every launch
  for (int i = idx0; i < 768 * 1024; i += stride) {
    int r = i >> 10, cc = i & 1023;
    wcat[i] = (r < 384) ? enc_Wih[r * 1024 + cc] : cenc_Wih[(r - 384) * 1024 + cc];
  }
  for (int i = idx0; i < 768; i += stride)
    bcat[i] = (i < 384) ? enc_bih[i] : cenc_bih[i - 384];
  for (int i = idx0; i < 2048; i += stride) {
    bias0[i] = l0_bih[i] + l0_bhh[i];
    bias1[i] = l1_bih[i] + l1_bhh[i];
  }
  for (int i = idx0; i < 4 * 4 * 128 * 256; i += stride) {
    int j = i & 255;
    int e = (i >> 8) & 127;
    int p = (i >> 15) & 3;
    int ld = i >> 17;  // layer*2 + dir
    const float* W = (ld < 2 ? l0_Whh : l1_Whh) + (ld & 1) * 1024 * 256;
    int gate = j >> 6, m = j & 63;
    int R = gate * 256 + 64 * p + m;
    wprep5[i] = pack_h2(W[R * 256 + 2 * e], W[R * 256 + 2 * e + 1]);
  }
  for (int i = idx0; i < 2 * 64 * 384; i += stride) {
    int row = i % 384;
    int e = (i / 384) & 63;
    int g2 = i / (64 * 384);
    const float* W = g2 ? cenc_Whh : enc_Whh;   // dir0 at base
    wgru[i] = pack_h2(W[row * 128 + 2 * e], W[row * 128 + 2 * e + 1]);
  }
}

// ---------------- fp32 tiled GEMM: C[M][N] = A[M][K] * B[N][K]^T + bias[N] ----------------
__global__ __launch_bounds__(256) void gemm_bt(
    const float* __restrict__ A, const float* __restrict__ B,
    const float* __restrict__ bias, float* __restrict__ C,
    int M, int N, int K) {
  __shared__ float As[16][68];
  __shared__ float Bs[16][68];
  int tid = threadIdx.x;
  int tx = tid & 15, ty = tid >> 4;
  int m0 = blockIdx.y * 64, n0 = blockIdx.x * 64;
  int lr = tid >> 2;
  int lc = (tid & 3) << 2;
  float acc[4][4] = {};
  const float* Ap = A + (long)(m0 + lr) * K + lc;
  const float* Bp = B + (long)(n0 + lr) * K + lc;
  for (int k0 = 0; k0 < K; k0 += 16) {
    float4 a4 = *(const float4*)(Ap + k0);
    float4 b4 = *(const float4*)(Bp + k0);
    __syncthreads();
    As[lc + 0][lr] = a4.x; As[lc + 1][lr] = a4.y; As[lc + 2][lr] = a4.z; As[lc + 3][lr] = a4.w;
    Bs[lc + 0][lr] = b4.x; Bs[lc + 1][lr] = b4.y; Bs[lc + 2][lr] = b4.z; Bs[lc + 3][lr] = b4.w;
    __syncthreads();
#pragma unroll
    for (int kk = 0; kk < 16; kk++) {
      float4 ra = *(const float4*)&As[kk][ty << 2];
      float4 rb = *(const float4*)&Bs[kk][tx << 2];
      float av[4] = {ra.x, ra.y, ra.z, ra.w};
      float bv[4] = {rb.x, rb.y, rb.z, rb.w};
#pragma unroll
      for (int i = 0; i < 4; i++)
#pragma unroll
        for (int jj = 0; jj < 4; jj++)
          acc[i][jj] += av[i] * bv[jj];
    }
  }
#pragma unroll
  for (int i = 0; i < 4; i++) {
    int m = m0 + (ty << 2) + i;
#pragma unroll
    for (int jj = 0; jj < 4; jj++) {
      int n = n0 + (tx << 2) + jj;
      C[(long)m * N + n] = acc[i][jj] + (bias ? bias[n] : 0.f);
    }
  }
}

// ---------------- GRU: 256 threads ----------------
__global__ __launch_bounds__(256) void gru2(
    const float* __restrict__ xgg,   // [T][768]
    const float* __restrict__ c_in,  // [T][1024]
    const unsigned* __restrict__ wgru,
    const float* __restrict__ enc_Wih, const float* __restrict__ enc_bih,
    const float* __restrict__ enc_bhh,
    const float* __restrict__ cenc_Wih, const float* __restrict__ cenc_bih,
    const float* __restrict__ cenc_bhh,
    float* __restrict__ u_out, float* __restrict__ cmem_out) {
  int b = blockIdx.x, j = threadIdx.x;
  __shared__ __align__(16) unsigned h2g[64];
  __shared__ float zs[128];
  const bool dual = j < 128;
  if (b < 2) {
    const unsigned* wg = wgru + b * (64 * 384);
    const float* bhh = b ? cenc_bhh : enc_bhh;
    unsigned w0[64], w1[64];
#pragma unroll
    for (int e = 0; e < 64; ++e) w0[e] = wg[e * 384 + j];
    float bh0 = bhh[j], bh1 = 0.f;
    if (dual) {
#pragma unroll
      for (int e = 0; e < 64; ++e) w1[e] = wg[e * 384 + 256 + j];
      bh1 = bhh[256 + j];
    }
    if (j < 64) h2g[j] = 0u;
    float hreg = 0.f;
    __syncthreads();
    const float* xp = xgg + b * 384;
    float x0 = xp[j];
    float x1 = dual ? xp[256 + j] : 0.f;
    for (int t = 0; t < kT; ++t) {
      float x0n = 0.f, x1n = 0.f;
      if (t + 1 < kT) {
        x0n = xp[(t + 1) * 768 + j];
        if (dual) x1n = xp[(t + 1) * 768 + 256 + j];
      }
      const uint4* h4 = (const uint4*)h2g;
      float a0 = 0.f, a1 = 0.f;
#pragma unroll
      for (int k = 0; k < 16; ++k) {
        uint4 hh = h4[k];
        a0 = fdot2u(w0[4 * k + 0], hh.x, a0);
        a0 = fdot2u(w0[4 * k + 1], hh.y, a0);
        a0 = fdot2u(w0[4 * k + 2], hh.z, a0);
        a0 = fdot2u(w0[4 * k + 3], hh.w, a0);
        if (dual) {
          a1 = fdot2u(w1[4 * k + 0], hh.x, a1);
          a1 = fdot2u(w1[4 * k + 1], hh.y, a1);
          a1 = fdot2u(w1[4 * k + 2], hh.z, a1);
          a1 = fdot2u(w1[4 * k + 3], hh.w, a1);
        }
      }
      if (!dual) zs[j - 128] = sigm(x0 + a0 + bh0);
      __syncthreads();
      if (dual) {
        float r = sigm(x0 + a0 + bh0);
        float n = tanh_f(x1 + r * (a1 + bh1));
        float z = zs[j];
        hreg = (1.f - z) * n + z * hreg;
        float hx = __shfl_xor(hreg, 1);
        if (!(j & 1)) h2g[j >> 1] = pack_h2(hreg, hx);
      }
      __syncthreads();
      x0 = x0n; x1 = x1n;
    }
    if (dual) { if (b == 0) u_out[j] = hreg; else cmem_out[j] = hreg; }
  } else {
    const float* Wih = ((b == 2) ? enc_Wih : cenc_Wih) + 384 * 1024;
    const float* bih = ((b == 2) ? enc_bih : cenc_bih) + 384;
    const float* bhh = ((b == 2) ? enc_bhh : cenc_bhh) + 384;
    const float* crow = c_in + (long)(kT - 1) * 1024;
    float a0 = bih[j], a1 = 0.f;
    {
      const float* wr = Wih + (long)j * 1024;
      for (int k = 0; k < 1024; k += 4) {
        float4 cv = *(const float4*)&crow[k];
        float4 wv = *(const float4*)&wr[k];
        a0 += cv.x * wv.x + cv.y * wv.y + cv.z * wv.z + cv.w * wv.w;
      }
    }
    if (dual) {
      a1 = bih[256 + j];
      const float* wr = Wih + (long)(256 + j) * 1024;
      for (int k = 0; k < 1024; k += 4) {
        float4 cv = *(const float4*)&crow[k];
        float4 wv = *(const float4*)&wr[k];
        a1 += cv.x * wv.x + cv.y * wv.y + cv.z * wv.z + cv.w * wv.w;
      }
    }
    if (!dual) zs[j - 128] = sigm(a0 + bhh[j]);
    __syncthreads();
    if (dual) {
      float r = sigm(a0 + bhh[j]);
      float n = tanh_f(a1 + r * bhh[256 + j]);
      float z = zs[j];
      float h = (1.f - z) * n;
      if (b == 2) u_out[128 + j] = h; else cmem_out[128 + j] = h;
    }
  }
}

// ---------------- attention ----------------
__global__ __launch_bounds__(256) void attn_dots(
    const float* __restrict__ mem, const float* __restrict__ u, float* __restrict__ d) {
  __shared__ float us[256];
  int tid = threadIdx.x;
  us[tid] = u[tid];
  __syncthreads();
  int g = tid >> 3, l8 = tid & 7;
  int row = blockIdx.x * 32 + g;
  const float* mr = mem + (long)row * 256 + l8 * 32;
  float p = 0.f;
#pragma unroll
  for (int k = 0; k < 32; k += 4) {
    float4 m4 = *(const float4*)&mr[k];
    p += m4.x * us[l8 * 32 + k] + m4.y * us[l8 * 32 + k + 1] +
         m4.z * us[l8 * 32 + k + 2] + m4.w * us[l8 * 32 + k + 3];
  }
  p += __shfl_down(p, 4);
  p += __shfl_down(p, 2);
  p += __shfl_down(p, 1);
  if (l8 == 0) d[row] = p;
}

__global__ __launch_bounds__(1024) void attn_soft(
    const float* __restrict__ d, float* __restrict__ p, float* __restrict__ h_acc) {
  __shared__ float red[1024];
  int tid = threadIdx.x;
  float v[8];
  float mx = -1e30f;
#pragma unroll
  for (int i = 0; i < 8; i++) { v[i] = d[tid * 8 + i]; mx = fmaxf(mx, v[i]); }
  red[tid] = mx; __syncthreads();
  for (int s = 512; s > 0; s >>= 1) {
    if (tid < s) red[tid] = fmaxf(red[tid], red[tid + s]);
    __syncthreads();
  }
  mx = red[0]; __syncthreads();
  float sm = 0.f; float e[8];
#pragma unroll
  for (int i = 0; i < 8; i++) { e[i] = __expf(v[i] - mx); sm += e[i]; }
  red[tid] = sm; __syncthreads();
  for (int s = 512; s > 0; s >>= 1) {
    if (tid < s) red[tid] += red[tid + s];
    __syncthreads();
  }
  float rz = 1.f / red[0];
#pragma unroll
  for (int i = 0; i < 8; i++) p[tid * 8 + i] = e[i] * rz;
  if (tid < 256) h_acc[tid] = 0.f;
}

__global__ __launch_bounds__(256) void attn_h(
    const float* __restrict__ mem, const float* __restrict__ p, float* __restrict__ h_acc) {
  int tid = threadIdx.x;
  int r0 = blockIdx.x * 128;
  float acc = 0.f;
  for (int i = 0; i < 128; i++) acc += p[r0 + i] * mem[(long)(r0 + i) * 256 + tid];
  atomicAdd(&h_acc[tid], acc);
}

__global__ __launch_bounds__(128) void attn_o(
    const float* __restrict__ u, const float* __restrict__ h_acc,
    const float* __restrict__ know_W, const float* __restrict__ know_b,
    float* __restrict__ o) {
  __shared__ float uh[256];
  int tid = threadIdx.x;
  uh[tid] = u[tid] + h_acc[tid];
  uh[128 + tid] = u[128 + tid] + h_acc[128 + tid];
  __syncthreads();
  int row = blockIdx.x * 128 + tid;
  float acc = know_b[row];
  for (int k = 0; k < 256; k += 4) {
    float4 w4 = *(const float4*)&know_W[row * 256 + k];
    acc += w4.x * uh[k] + w4.y * uh[k + 1] + w4.z * uh[k + 2] + w4.w * uh[k + 3];
  }
  o[row] = acc;
}

__global__ __launch_bounds__(128) void attn_ov(
    const float* __restrict__ o, const float* __restrict__ Wih0, float* __restrict__ ov) {
  int row = blockIdx.x * 128 + threadIdx.x;
  float acc = 0.f;
  for (int k = 0; k < 1024; k += 4) {
    float4 w4 = *(const float4*)&Wih0[(long)row * 1024 + k];
    float4 o4 = *(const float4*)&o[k];
    acc += w4.x * o4.x + w4.y * o4.y + w4.z * o4.z + w4.w * o4.w;
  }
  ov[row] = acc;
}

// ---------------- LSTM v19: single-wave blocks, gate-complete threads ----------------
// grid = 32; active: bid&7 in {0,1}; dir = bid&7, p = bid>>3. 64 threads (1 wave).
// Thread m owns ALL FOUR gate rows {i,f,g,o} of h-elem (64p+m): the cell update is
// thread-local -> no gact exchange, no cross-wave barrier; single wave = lockstep.
// Weights in LDS slab [256 rows][130 u32] (stride 130 % 32 == 2 -> uniform 8
// words/bank on b128: conflict-free). h reads same-address -> broadcast.
// Poll hidden: issue 3-peer tagged-u64 loads, compute own-quarter chunks, then check.
__global__ __launch_bounds__(64) void lstm_w1(
    const unsigned* __restrict__ wp5,    // layer base: [dir<2][p<4][e<128][r<256]
    const float* __restrict__ xg,        // [T][2048] (biases folded)
    const float* __restrict__ extra,     // [2048] rank-1 add or nullptr
    float* __restrict__ out,             // [T][512]
    u64* __restrict__ pay) {             // layer base: [dir*4+p][slot<2][32] u64
  const int bid = blockIdx.x;
  const int xs = bid & 7;
  if (xs >= 2) return;
  const int dir = xs, p = bid >> 3;
  const int m = threadIdx.x;             // h-elem local [0,64)

  __shared__ __align__(16) unsigned wl[256 * 130];  // 133120 B
  __shared__ __align__(16) unsigned h2v[128];

  const unsigned* base = wp5 + (size_t)dir * 131072 + (size_t)p * 32768;
  for (int i = m; i < 32768; i += 64) {
    int r = i & 255, e = i >> 8;
    wl[r * 130 + e] = base[e * 256 + r];
  }
  float ex[4] = {0.f, 0.f, 0.f, 0.f};
  if (extra) {
#pragma unroll
    for (int g = 0; g < 4; ++g) ex[g] = extra[dir * 1024 + g * 256 + 64 * p + m];
  }
  h2v[m] = 0u; h2v[64 + m] = 0u;
  float cst = 0.f;
  __syncthreads();

  const int bi = dir * 4 + p;
  u64* mypay = pay + bi * 64;
  const int pA = (p + 1) & 3, pB = (p + 2) & 3, pC = (p + 3) & 3;
  u64* payA = pay + (dir * 4 + pA) * 64;
  u64* payB = pay + (dir * 4 + pB) * 64;
  u64* payC = pay + (dir * 4 + pC) * 64;

  const float* xp = xg + dir * 1024;
  const int t0 = dir ? (kT - 1) : 0;
  const int dt = dir ? -1 : 1;
  const int wb0 = (0 * 64 + m) * 130, wb1 = (1 * 64 + m) * 130;
  const int wb2 = (2 * 64 + m) * 130, wb3 = (3 * 64 + m) * 130;

  float xc[4];
#pragma unroll
  for (int g = 0; g < 4; ++g)
    xc[g] = xp[(long)t0 * 2048 + g * 256 + 64 * p + m] + ex[g];

  for (int s = 0; s < kT; ++s) {
    const int t = t0 + s * dt;
    float xn[4] = {0.f, 0.f, 0.f, 0.f};
    if (s + 1 < kT) {
      const float* xr = xp + (long)(t + dt) * 2048;
#pragma unroll
      for (int g = 0; g < 4; ++g) xn[g] = xr[g * 256 + 64 * p + m];
    }
    // 1. issue peer payload loads (lanes <32: peers A,B; lanes >=32: peer C)
    const int slot = (s & 1) * 32;
    u64 vA = 0, vB = 0;
    if (s > 0) {
      if (m < 32) {
        vA = __hip_atomic_load(&payA[slot + m], __ATOMIC_RELAXED, __HIP_MEMORY_SCOPE_AGENT);
        vB = __hip_atomic_load(&payB[slot + m], __ATOMIC_RELAXED, __HIP_MEMORY_SCOPE_AGENT);
      } else {
        vA = __hip_atomic_load(&payC[slot + (m - 32)], __ATOMIC_RELAXED, __HIP_MEMORY_SCOPE_AGENT);
      }
    }
    // 2. own-quarter partial dot (chunks 8p..8p+8) while loads are in flight
    const uint4* h4 = (const uint4*)h2v;
    float a0 = xc[0], a1 = xc[1], a2 = xc[2], a3 = xc[3];
#pragma unroll
    for (int k = 0; k < 8; ++k) {
      const int c = 8 * p + k;
      uint4 hh = h4[c];
      uint4 w0 = *(const uint4*)&wl[wb0 + 4 * c];
      uint4 w1 = *(const uint4*)&wl[wb1 + 4 * c];
      uint4 w2 = *(const uint4*)&wl[wb2 + 4 * c];
      uint4 w3 = *(const uint4*)&wl[wb3 + 4 * c];
      a0 = fdot2u(w0.x, hh.x, a0); a0 = fdot2u(w0.y, hh.y, a0);
      a0 = fdot2u(w0.z, hh.z, a0); a0 = fdot2u(w0.w, hh.w, a0);
      a1 = fdot2u(w1.x, hh.x, a1); a1 = fdot2u(w1.y, hh.y, a1);
      a1 = fdot2u(w1.z, hh.z, a1); a1 = fdot2u(w1.w, hh.w, a1);
      a2 = fdot2u(w2.x, hh.x, a2); a2 = fdot2u(w2.y, hh.y, a2);
      a2 = fdot2u(w2.z, hh.z, a2); a2 = fdot2u(w2.w, hh.w, a2);
      a3 = fdot2u(w3.x, hh.x, a3); a3 = fdot2u(w3.y, hh.y, a3);
      a3 = fdot2u(w3.z, hh.z, a3); a3 = fdot2u(w3.w, hh.w, a3);
    }
    // 3. finish poll, write peer h-quarters
    if (s > 0) {
      int guard = 0;
      if (m < 32) {
        while ((unsigned)(vA >> 32) < (unsigned)s && ++guard < (1 << 18))
          vA = __hip_atomic_load(&payA[slot + m], __ATOMIC_RELAXED, __HIP_MEMORY_SCOPE_AGENT);
        h2v[32 * pA + m] = (unsigned)vA;
        guard = 0;
        while ((unsigned)(vB >> 32) < (unsigned)s && ++guard < (1 << 18))
          vB = __hip_atomic_load(&payB[slot + m], __ATOMIC_RELAXED, __HIP_MEMORY_SCOPE_AGENT);
        h2v[32 * pB + m] = (unsigned)vB;
      } else {
        while ((unsigned)(vA >> 32) < (unsigned)s && ++guard < (1 << 18))
          vA = __hip_atomic_load(&payC[slot + (m - 32)], __ATOMIC_RELAXED, __HIP_MEMORY_SCOPE_AGENT);
        h2v[32 * pC + (m - 32)] = (unsigned)vA;
      }
    }
    __syncthreads();   // single wave: ~free; orders h2v writes before reads
    // 4. peer chunks (24 of 32)
#pragma unroll
    for (int cc = 0; cc < 24; ++cc) {
      const int c = cc + (cc >= 8 * p ? 8 : 0);
      uint4 hh = h4[c];
      uint4 w0 = *(const uint4*)&wl[wb0 + 4 * c];
      uint4 w1 = *(const uint4*)&wl[wb1 + 4 * c];
      uint4 w2 = *(const uint4*)&wl[wb2 + 4 * c];
      uint4 w3 = *(const uint4*)&wl[wb3 + 4 * c];
      a0 = fdot2u(w0.x, hh.x, a0); a0 = fdot2u(w0.y, hh.y, a0);
      a0 = fdot2u(w0.z, hh.z, a0); a0 = fdot2u(w0.w, hh.w, a0);
      a1 = fdot2u(w1.x, hh.x, a1); a1 = fdot2u(w1.y, hh.y, a1);
      a1 = fdot2u(w1.z, hh.z, a1); a1 = fdot2u(w1.w, hh.w, a1);
      a2 = fdot2u(w2.x, hh.x, a2); a2 = fdot2u(w2.y, hh.y, a2);
      a2 = fdot2u(w2.z, hh.z, a2); a2 = fdot2u(w2.w, hh.w, a2);
      a3 = fdot2u(w3.x, hh.x, a3); a3 = fdot2u(w3.y, hh.y, a3);
      a3 = fdot2u(w3.z, hh.z, a3); a3 = fdot2u(w3.w, hh.w, a3);
    }
    // 5. thread-local cell update (i,f,g,o all here)
    float iv = sigm(a0);
    float fv = sigm(a1);
    float gv = tanh_f(a2);
    float ov = sigm(a3);
    cst = fv * cst + iv * gv;
    float h = ov * tanh_f(cst);
    out[(long)t * 512 + dir * 256 + 64 * p + m] = h;
    float hx = __shfl_xor(h, 1);
    if (!(m & 1)) {
      int idx = m >> 1;                       // 0..31
      unsigned hp = pack_h2(h, hx);
      h2v[32 * p + idx] = hp;                 // own quarter for next step
      u64 tagged = ((u64)(unsigned)(s + 1) << 32) | (u64)hp;
      __hip_atomic_store(&mypay[((s + 1) & 1) * 32 + idx], tagged,
                         __ATOMIC_RELAXED, __HIP_MEMORY_SCOPE_AGENT);
    }
    __syncthreads();   // ~free; orders own h2v write before next-step reads
#pragma unroll
    for (int g = 0; g < 4; ++g) xc[g] = xn[g] + ex[g];
  }
}

// ---------------- final row softmax ----------------
__global__ __launch_bounds__(256) void softmax_rows(
    const float* __restrict__ logits, float* __restrict__ outp) {
  int t = blockIdx.x, tid = threadIdx.x;
  __shared__ float red[256];
  const float* lr = logits + (long)t * 4096;
  float v[16];
  float mx = -1e30f;
#pragma unroll
  for (int i = 0; i < 16; i++) { v[i] = lr[tid + 256 * i]; mx = fmaxf(mx, v[i]); }
  red[tid] = mx; __syncthreads();
  for (int s = 128; s > 0; s >>= 1) {
    if (tid < s) red[tid] = fmaxf(red[tid], red[tid + s]);
    __syncthreads();
  }
  mx = red[0]; __syncthreads();
  float sm = 0.f;
#pragma unroll
  for (int i = 0; i < 16; i++) { v[i] = __expf(v[i] - mx); sm += v[i]; }
  red[tid] = sm; __syncthreads();
  for (int s = 128; s > 0; s >>= 1) {
    if (tid < s) red[tid] += red[tid + s];
    __syncthreads();
  }
  float rz = 1.f / red[0];
#pragma unroll
  for (int i = 0; i < 16; i++) outp[(long)t * 4096 + tid + 256 * i] = v[i] * rz;
}

// ---------------- launch ----------------
extern "C" void kernel_launch(void* const* d_in, const int* in_sizes, int n_in,
                              void* d_out, int out_size, void* d_ws, size_t ws_size,
                              hipStream_t stream) {
  const float* c        = (const float*)d_in[0];
  const float* memory   = (const float*)d_in[1];
  const float* enc_Wih  = (const float*)d_in[2];
  const float* enc_Whh  = (const float*)d_in[3];
  const float* enc_bih  = (const float*)d_in[4];
  const float* enc_bhh  = (const float*)d_in[5];
  const float* cenc_Wih = (const float*)d_in[6];
  const float* cenc_Whh = (const float*)d_in[7];
  const float* cenc_bih = (const float*)d_in[8];
  const float* cenc_bhh = (const float*)d_in[9];
  const float* know_W   = (const float*)d_in[10];
  const float* know_b   = (const float*)d_in[11];
  const float* l0_Wih   = (const float*)d_in[12];
  const float* l0_Whh   = (const float*)d_in[13];
  const float* l0_bih   = (const float*)d_in[14];
  const float* l0_bhh   = (const float*)d_in[15];
  const float* l1_Wih   = (const float*)d_in[16];
  const float* l1_Whh   = (const float*)d_in[17];
  const float* l1_bih   = (const float*)d_in[18];
  const float* l1_bhh   = (const float*)d_in[19];
  const float* out_W    = (const float*)d_in[20];
  const float* out_b    = (const float*)d_in[21];

  float* ws = (float*)d_ws;
  float* outp = (float*)d_out;

  float* xgg   = ws;                  // 1,572,864   [T][768]
  float* cW    = ws + 1572864;        // 4,194,304   [T][2048]
  float* wcat  = ws + 5767168;        //   786,432
  float* l0out = ws + 6553600;        // 1,048,576   [T][512]
  float* xg1   = ws + 7602176;        // 4,194,304   [T][2048]
  unsigned* wprep5 = (unsigned*)(ws + 11796480);  // 524,288 u32 (2 MB)
  float* bcat  = ws + 12320768;       // 768
  float* bias0 = ws + 12321536;       // 2048
  float* bias1 = ws + 12323584;       // 2048
  float* u_vec = ws + 12325632;       // 256
  float* d_att = ws + 12325888;       // 8192
  float* p_att = ws + 12334080;       // 8192
  float* h_acc = ws + 12342272;       // 256
  float* o_vec = ws + 12342528;       // 1024
  float* ov    = ws + 12343552;       // 2048
  float* l1out = ws + 12345600;       // 1,048,576  (ends 13,394,176)
  unsigned* wgru = (unsigned*)(ws + 13656320);      // 49,152 u32
  u64* payload = (u64*)(ws + 13705472);             // 1024 u64 (2 layers × 8 blk × 64)
  float* logits = ws;                 // 8,388,608   aliases early regions

  prep_kernel<<<512, 256, 0, stream>>>(enc_Wih, enc_bih, cenc_Wih, cenc_bih,
                                       enc_Whh, cenc_Whh,
                                       l0_Whh, l1_Whh, l0_bih, l0_bhh, l1_bih, l1_bhh,
                                       wcat, bcat, bias0, bias1, wprep5, wgru, payload);
  gemm_bt<<<dim3(768 / 64, 2048 / 64), 256, 0, stream>>>(c, wcat, bcat, xgg, 2048, 768, 1024);
  gemm_bt<<<dim3(2048 / 64, 2048 / 64), 256, 0, stream>>>(c, l0_Wih, bias0, cW, 2048, 2048, 1024);
  gru2<<<4, 256, 0, stream>>>(xgg, c, wgru, enc_Wih, enc_bih, enc_bhh,
                              cenc_Wih, cenc_bih, cenc_bhh,
                              u_vec, outp + kOUT_ELEMS);
  attn_dots<<<256, 256, 0, stream>>>(memory, u_vec, d_att);
  attn_soft<<<1, 1024, 0, stream>>>(d_att, p_att, h_acc);
  attn_h<<<64, 256, 0, stream>>>(memory, p_att, h_acc);
  attn_o<<<8, 128, 0, stream>>>(u_vec, h_acc, know_W, know_b, o_vec);
  attn_ov<<<16, 128, 0, stream>>>(o_vec, l0_Wih, ov);
  lstm_w1<<<32, 64, 0, stream>>>(wprep5, cW, ov, l0out, payload);
  gemm_bt<<<dim3(2048 / 64, 2048 / 64), 256, 0, stream>>>(l0out, l1_Wih, bias1, xg1, 2048, 2048, 512);
  lstm_w1<<<32, 64, 0, stream>>>(wprep5 + 262144, xg1, nullptr, l1out, payload + 512);
  gemm_bt<<<dim3(4096 / 64, 2048 / 64), 256, 0, stream>>>(l1out, out_W, out_b, logits, 2048, 4096, 512);
  softmax_rows<<<2048, 256, 0, stream>>>(logits, outp);
}

// Round 20
// 7184.135 us; speedup vs baseline: 1.9483x; 1.9483x over previous
//
#include <hip/hip_runtime.h>
#include <hip/hip_bf16.h>

// ---------------- constants ----------------
static constexpr int kT    = 2048;
static constexpr int kOUT_ELEMS = 2048 * 4096;   // output 0 size

typedef _Float16 half2_t __attribute__((ext_vector_type(2)));
typedef _Float16 half8_t __attribute__((ext_vector_type(8)));
typedef float f32x4_t __attribute__((ext_vector_type(4)));
typedef unsigned long long u64;

__device__ __forceinline__ unsigned pack_h2(float a, float b) {
  half2_t h{(_Float16)a, (_Float16)b};
  return __builtin_bit_cast(unsigned, h);
}
__device__ __forceinline__ float fdot2u(unsigned a, unsigned b, float c) {
  return __builtin_amdgcn_fdot2(__builtin_bit_cast(half2_t, a),
                                __builtin_bit_cast(half2_t, b), c, false);
}
__device__ __forceinline__ float sigm(float x) {
  return 1.f / (1.f + __expf(-x));
}
__device__ __forceinline__ float tanh_f(float x) {
  float ax = fabsf(x);
  float e = __expf(-2.f * ax);
  float r = (1.f - e) / (1.f + e);
  return x < 0.f ? -r : r;
}

// ---------------- K0: prep ----------------
// wprep5 [ld<4][p<4][e<128][j<256]; wgru [g2<2][e<64][row<384]; payload tags zeroed;
// fp16 copies: c16, wcat16, l0W16, l1W16, outW16.
__global__ __launch_bounds__(256) void prep_kernel(
    const float* __restrict__ c_in,
    const float* __restrict__ enc_Wih, const float* __restrict__ enc_bih,
    const float* __restrict__ cenc_Wih, const float* __restrict__ cenc_bih,
    const float* __restrict__ enc_Whh, const float* __restrict__ cenc_Whh,
    const float* __restrict__ l0_Wih, const float* __restrict__ l0_Whh,
    const float* __restrict__ l1_Wih, const float* __restrict__ l1_Whh,
    const float* __restrict__ out_W,
    const float* __restrict__ l0_bih, const float* __restrict__ l0_bhh,
    const float* __restrict__ l1_bih, const float* __restrict__ l1_bhh,
    float* __restrict__ bcat,
    float* __restrict__ bias0, float* __restrict__ bias1,
    unsigned* __restrict__ wprep5, unsigned* __restrict__ wgru,
    u64* __restrict__ payz,
    _Float16* __restrict__ c16, _Float16* __restrict__ wcat16,
    _Float16* __restrict__ l0W16, _Float16* __restrict__ l1W16,
    _Float16* __restrict__ outW16) {
  int idx0 = blockIdx.x * blockDim.x + threadIdx.x;
  int stride = gridDim.x * blockDim.x;
  for (int i = idx0; i < 1024; i += stride) payz[i] = 0ull;   // re-zero every launch
  for (int i = idx0; i < 768; i += stride)
    bcat[i] = (i < 384) ? enc_bih[i] : cenc_bih[i - 384];
  for (int i = idx0; i < 2048; i += stride) {
    bias0[i] = l0_bih[i] + l0_bhh[i];
    bias1[i] = l1_bih[i] + l1_bhh[i];
  }
  for (int i = idx0; i < 4 * 4 * 128 * 256; i += stride) {
    int j = i & 255;
    int e = (i >> 8) & 127;
    int p = (i >> 15) & 3;
    int ld = i >> 17;  // layer*2 + dir
    const float* W = (ld < 2 ? l0_Whh : l1_Whh) + (ld & 1) * 1024 * 256;
    int gate = j >> 6, m = j & 63;
    int R = gate * 256 + 64 * p + m;
    wprep5[i] = pack_h2(W[R * 256 + 2 * e], W[R * 256 + 2 * e + 1]);
  }
  for (int i = idx0; i < 2 * 64 * 384; i += stride) {
    int row = i % 384;
    int e = (i / 384) & 63;
    int g2 = i / (64 * 384);
    const float* W = g2 ? cenc_Whh : enc_Whh;   // dir0 at base
    wgru[i] = pack_h2(W[row * 128 + 2 * e], W[row * 128 + 2 * e + 1]);
  }
  // fp16 copies for MFMA GEMMs
  for (int i = idx0; i < 2048 * 1024; i += stride) c16[i] = (_Float16)c_in[i];
  for (int i = idx0; i < 768 * 1024; i += stride) {
    int r = i >> 10, cc = i & 1023;
    float v = (r < 384) ? enc_Wih[r * 1024 + cc] : cenc_Wih[(r - 384) * 1024 + cc];
    wcat16[i] = (_Float16)v;
  }
  for (int i = idx0; i < 2048 * 1024; i += stride) l0W16[i] = (_Float16)l0_Wih[i];
  for (int i = idx0; i < 2048 * 512; i += stride)  l1W16[i] = (_Float16)l1_Wih[i];
  for (int i = idx0; i < 4096 * 512; i += stride)  outW16[i] = (_Float16)out_W[i];
}

// ---------------- fp32->fp16 convert ----------------
__global__ __launch_bounds__(256) void cvt16(
    const float* __restrict__ in, _Float16* __restrict__ out, int n) {
  int i = (blockIdx.x * 256 + threadIdx.x) * 4;
  if (i < n) {
    float4 v = *(const float4*)&in[i];
    out[i + 0] = (_Float16)v.x;
    out[i + 1] = (_Float16)v.y;
    out[i + 2] = (_Float16)v.z;
    out[i + 3] = (_Float16)v.w;
  }
}

// ---------------- MFMA GEMM: C[M][N] = A[M][K] * B[N][K]^T + bias[N] ----------------
// fp16 inputs, fp32 accumulate. Per wave: 16m x 64n strip; block = 4 waves = 64x64.
// Fragments (v_mfma_f32_16x16x32_f16): lane l, elem j: A[l&15][(l>>4)*8+j],
// B^T[(l>>4)*8+j][l&15] = W[l&15][(l>>4)*8+j] (same pattern, mirrored layouts;
// shared lane->k map cancels). C/D: col=lane&15, row=(lane>>4)*4+reg [m89-verified].
__global__ __launch_bounds__(256) void gemm_mfma(
    const _Float16* __restrict__ A,   // [M][K]
    const _Float16* __restrict__ B,   // [N][K]
    const float* __restrict__ bias,   // [N] or nullptr
    float* __restrict__ C,            // [M][N]
    int M, int N, int K) {
  const int wave = threadIdx.x >> 6, lane = threadIdx.x & 63;
  const int r = lane & 15, kg = lane >> 4;
  const int m0 = blockIdx.y * 64 + wave * 16;
  const int n0 = blockIdx.x * 64;
  const _Float16* ap = A + (size_t)(m0 + r) * K + kg * 8;
  const _Float16* bp = B + (size_t)(n0 + r) * K + kg * 8;
  f32x4_t acc0 = {0.f, 0.f, 0.f, 0.f};
  f32x4_t acc1 = {0.f, 0.f, 0.f, 0.f};
  f32x4_t acc2 = {0.f, 0.f, 0.f, 0.f};
  f32x4_t acc3 = {0.f, 0.f, 0.f, 0.f};
  for (int k0 = 0; k0 < K; k0 += 32) {
    half8_t av = *(const half8_t*)(ap + k0);
    half8_t b0 = *(const half8_t*)(bp + k0);
    half8_t b1 = *(const half8_t*)(bp + (size_t)16 * K + k0);
    half8_t b2 = *(const half8_t*)(bp + (size_t)32 * K + k0);
    half8_t b3 = *(const half8_t*)(bp + (size_t)48 * K + k0);
    acc0 = __builtin_amdgcn_mfma_f32_16x16x32_f16(av, b0, acc0, 0, 0, 0);
    acc1 = __builtin_amdgcn_mfma_f32_16x16x32_f16(av, b1, acc1, 0, 0, 0);
    acc2 = __builtin_amdgcn_mfma_f32_16x16x32_f16(av, b2, acc2, 0, 0, 0);
    acc3 = __builtin_amdgcn_mfma_f32_16x16x32_f16(av, b3, acc3, 0, 0, 0);
  }
  float bv0 = bias ? bias[n0 + r]      : 0.f;
  float bv1 = bias ? bias[n0 + 16 + r] : 0.f;
  float bv2 = bias ? bias[n0 + 32 + r] : 0.f;
  float bv3 = bias ? bias[n0 + 48 + r] : 0.f;
  const int row0 = m0 + 4 * kg;
#pragma unroll
  for (int i = 0; i < 4; ++i) {
    float* cr = C + (size_t)(row0 + i) * N + n0 + r;
    cr[0]  = acc0[i] + bv0;
    cr[16] = acc1[i] + bv1;
    cr[32] = acc2[i] + bv2;
    cr[48] = acc3[i] + bv3;
  }
}

// ---------------- GRU: 256 threads ----------------
__global__ __launch_bounds__(256) void gru2(
    const float* __restrict__ xgg,   // [T][768]
    const float* __restrict__ c_in,  // [T][1024]
    const unsigned* __restrict__ wgru,
    const float* __restrict__ enc_Wih, const float* __restrict__ enc_bih,
    const float* __restrict__ enc_bhh,
    const float* __restrict__ cenc_Wih, const float* __restrict__ cenc_bih,
    const float* __restrict__ cenc_bhh,
    float* __restrict__ u_out, float* __restrict__ cmem_out) {
  int b = blockIdx.x, j = threadIdx.x;
  __shared__ __align__(16) unsigned h2g[64];
  __shared__ float zs[128];
  const bool dual = j < 128;
  if (b < 2) {
    const unsigned* wg = wgru + b * (64 * 384);
    const float* bhh = b ? cenc_bhh : enc_bhh;
    unsigned w0[64], w1[64];
#pragma unroll
    for (int e = 0; e < 64; ++e) w0[e] = wg[e * 384 + j];
#pragma unroll
    for (int e = 0; e < 64; ++e) asm volatile("" : "+v"(w0[e]));
    float bh0 = bhh[j], bh1 = 0.f;
    if (dual) {
#pragma unroll
      for (int e = 0; e < 64; ++e) w1[e] = wg[e * 384 + 256 + j];
#pragma unroll
      for (int e = 0; e < 64; ++e) asm volatile("" : "+v"(w1[e]));
      bh1 = bhh[256 + j];
    }
    if (j < 64) h2g[j] = 0u;
    float hreg = 0.f;
    __syncthreads();
    const float* xp = xgg + b * 384;
    float x0 = xp[j];
    float x1 = dual ? xp[256 + j] : 0.f;
    for (int t = 0; t < kT; ++t) {
      float x0n = 0.f, x1n = 0.f;
      if (t + 1 < kT) {
        x0n = xp[(t + 1) * 768 + j];
        if (dual) x1n = xp[(t + 1) * 768 + 256 + j];
      }
      const uint4* h4 = (const uint4*)h2g;
      float a0 = 0.f, a1 = 0.f;
#pragma unroll
      for (int k = 0; k < 16; ++k) {
        uint4 hh = h4[k];
        a0 = fdot2u(w0[4 * k + 0], hh.x, a0);
        a0 = fdot2u(w0[4 * k + 1], hh.y, a0);
        a0 = fdot2u(w0[4 * k + 2], hh.z, a0);
        a0 = fdot2u(w0[4 * k + 3], hh.w, a0);
        if (dual) {
          a1 = fdot2u(w1[4 * k + 0], hh.x, a1);
          a1 = fdot2u(w1[4 * k + 1], hh.y, a1);
          a1 = fdot2u(w1[4 * k + 2], hh.z, a1);
          a1 = fdot2u(w1[4 * k + 3], hh.w, a1);
        }
      }
      if (!dual) zs[j - 128] = sigm(x0 + a0 + bh0);
      __syncthreads();
      if (dual) {
        float r = sigm(x0 + a0 + bh0);
        float n = tanh_f(x1 + r * (a1 + bh1));
        float z = zs[j];
        hreg = (1.f - z) * n + z * hreg;
        float hx = __shfl_xor(hreg, 1);
        if (!(j & 1)) h2g[j >> 1] = pack_h2(hreg, hx);
      }
      __syncthreads();
      x0 = x0n; x1 = x1n;
    }
    if (dual) { if (b == 0) u_out[j] = hreg; else cmem_out[j] = hreg; }
  } else {
    const float* Wih = ((b == 2) ? enc_Wih : cenc_Wih) + 384 * 1024;
    const float* bih = ((b == 2) ? enc_bih : cenc_bih) + 384;
    const float* bhh = ((b == 2) ? enc_bhh : cenc_bhh) + 384;
    const float* crow = c_in + (long)(kT - 1) * 1024;
    float a0 = bih[j], a1 = 0.f;
    {
      const float* wr = Wih + (long)j * 1024;
      for (int k = 0; k < 1024; k += 4) {
        float4 cv = *(const float4*)&crow[k];
        float4 wv = *(const float4*)&wr[k];
        a0 += cv.x * wv.x + cv.y * wv.y + cv.z * wv.z + cv.w * wv.w;
      }
    }
    if (dual) {
      a1 = bih[256 + j];
      const float* wr = Wih + (long)(256 + j) * 1024;
      for (int k = 0; k < 1024; k += 4) {
        float4 cv = *(const float4*)&crow[k];
        float4 wv = *(const float4*)&wr[k];
        a1 += cv.x * wv.x + cv.y * wv.y + cv.z * wv.z + cv.w * wv.w;
      }
    }
    if (!dual) zs[j - 128] = sigm(a0 + bhh[j]);
    __syncthreads();
    if (dual) {
      float r = sigm(a0 + bhh[j]);
      float n = tanh_f(a1 + r * bhh[256 + j]);
      float z = zs[j];
      float h = (1.f - z) * n;
      if (b == 2) u_out[128 + j] = h; else cmem_out[128 + j] = h;
    }
  }
}

// ---------------- attention ----------------
__global__ __launch_bounds__(256) void attn_dots(
    const float* __restrict__ mem, const float* __restrict__ u, float* __restrict__ d) {
  __shared__ float us[256];
  int tid = threadIdx.x;
  us[tid] = u[tid];
  __syncthreads();
  int g = tid >> 3, l8 = tid & 7;
  int row = blockIdx.x * 32 + g;
  const float* mr = mem + (long)row * 256 + l8 * 32;
  float p = 0.f;
#pragma unroll
  for (int k = 0; k < 32; k += 4) {
    float4 m4 = *(const float4*)&mr[k];
    p += m4.x * us[l8 * 32 + k] + m4.y * us[l8 * 32 + k + 1] +
         m4.z * us[l8 * 32 + k + 2] + m4.w * us[l8 * 32 + k + 3];
  }
  p += __shfl_down(p, 4);
  p += __shfl_down(p, 2);
  p += __shfl_down(p, 1);
  if (l8 == 0) d[row] = p;
}

__global__ __launch_bounds__(1024) void attn_soft(
    const float* __restrict__ d, float* __restrict__ p, float* __restrict__ h_acc) {
  __shared__ float red[1024];
  int tid = threadIdx.x;
  float v[8];
  float mx = -1e30f;
#pragma unroll
  for (int i = 0; i < 8; i++) { v[i] = d[tid * 8 + i]; mx = fmaxf(mx, v[i]); }
  red[tid] = mx; __syncthreads();
  for (int s = 512; s > 0; s >>= 1) {
    if (tid < s) red[tid] = fmaxf(red[tid], red[tid + s]);
    __syncthreads();
  }
  mx = red[0]; __syncthreads();
  float sm = 0.f; float e[8];
#pragma unroll
  for (int i = 0; i < 8; i++) { e[i] = __expf(v[i] - mx); sm += e[i]; }
  red[tid] = sm; __syncthreads();
  for (int s = 512; s > 0; s >>= 1) {
    if (tid < s) red[tid] += red[tid + s];
    __syncthreads();
  }
  float rz = 1.f / red[0];
#pragma unroll
  for (int i = 0; i < 8; i++) p[tid * 8 + i] = e[i] * rz;
  if (tid < 256) h_acc[tid] = 0.f;
}

__global__ __launch_bounds__(256) void attn_h(
    const float* __restrict__ mem, const float* __restrict__ p, float* __restrict__ h_acc) {
  int tid = threadIdx.x;
  int r0 = blockIdx.x * 128;
  float acc = 0.f;
  for (int i = 0; i < 128; i++) acc += p[r0 + i] * mem[(long)(r0 + i) * 256 + tid];
  atomicAdd(&h_acc[tid], acc);
}

__global__ __launch_bounds__(128) void attn_o(
    const float* __restrict__ u, const float* __restrict__ h_acc,
    const float* __restrict__ know_W, const float* __restrict__ know_b,
    float* __restrict__ o) {
  __shared__ float uh[256];
  int tid = threadIdx.x;
  uh[tid] = u[tid] + h_acc[tid];
  uh[128 + tid] = u[128 + tid] + h_acc[128 + tid];
  __syncthreads();
  int row = blockIdx.x * 128 + tid;
  float acc = know_b[row];
  for (int k = 0; k < 256; k += 4) {
    float4 w4 = *(const float4*)&know_W[row * 256 + k];
    acc += w4.x * uh[k] + w4.y * uh[k + 1] + w4.z * uh[k + 2] + w4.w * uh[k + 3];
  }
  o[row] = acc;
}

__global__ __launch_bounds__(128) void attn_ov(
    const float* __restrict__ o, const float* __restrict__ Wih0, float* __restrict__ ov) {
  int row = blockIdx.x * 128 + threadIdx.x;
  float acc = 0.f;
  for (int k = 0; k < 1024; k += 4) {
    float4 w4 = *(const float4*)&Wih0[(long)row * 1024 + k];
    float4 o4 = *(const float4*)&o[k];
    acc += w4.x * o4.x + w4.y * o4.y + w4.z * o4.z + w4.w * o4.w;
  }
  ov[row] = acc;
}

// ---------------- LSTM (R17, best known: 2.71 ms steady) ----------------
__global__ __launch_bounds__(256) void lstm_cc4(
    const unsigned* __restrict__ wp5,    // layer base: [dir<2][p<4][e<128][j<256]
    const float* __restrict__ xg,        // [T][2048] (biases folded)
    const float* __restrict__ extra,     // [2048] rank-1 add or nullptr
    float* __restrict__ out,             // [T][512]
    u64* __restrict__ pay) {             // layer base: [dir*4+p][slot<2][32] u64
  const int bid = blockIdx.x;
  const int xs = bid & 7;
  if (xs >= 2) return;                   // inactive filler blocks
  const int dir = xs, p = bid >> 3;      // p in [0,4)
  const int j = threadIdx.x;             // [0,256)
  const int gate = j >> 6;
  const int m = j & 63;
  const int R = gate * 256 + 64 * p + m; // global gate row

  __shared__ __align__(16) unsigned h2v[128];      // full h packed (h2)
  __shared__ float gact[256];

  const unsigned* base = wp5 + (size_t)dir * 131072 + (size_t)p * 32768;
  unsigned wv[128];
#pragma unroll
  for (int e = 0; e < 128; ++e) wv[e] = base[e * 256 + j];
#pragma unroll
  for (int e = 0; e < 128; ++e) asm volatile("" : "+v"(wv[e]));

  float exv = extra ? extra[dir * 1024 + R] : 0.f;
  if (j < 128) h2v[j] = 0u;
  float cst = 0.f;
  __syncthreads();

  const int bi = dir * 4 + p;
  u64* mypay = pay + bi * 64;
  const int pi = (j < 96) ? (j >> 5) : 0;
  const int pp = pi + (pi >= p ? 1 : 0);
  u64* peerpay = pay + (dir * 4 + pp) * 64;
  const int pidx = j & 31;

  const float* xp = xg + dir * 1024;
  const int t0 = dir ? (kT - 1) : 0;
  const int dt = dir ? -1 : 1;
  float xc = xp[(long)t0 * 2048 + R] + exv;

  for (int s = 0; s < kT; ++s) {
    const int t = t0 + s * dt;
    float xn_ = 0.f;
    if (s + 1 < kT) xn_ = xp[(long)(t + dt) * 2048 + R];
    if (j < 96 && s > 0) {
      u64 v;
      int guard = 0;
      do {
        v = __hip_atomic_load(&peerpay[(s & 1) * 32 + pidx],
                              __ATOMIC_RELAXED, __HIP_MEMORY_SCOPE_AGENT);
      } while ((unsigned)(v >> 32) < (unsigned)s && ++guard < (1 << 18));
      h2v[32 * pp + pidx] = (unsigned)v;
    }
    __syncthreads();
    const uint4* h4 = (const uint4*)h2v;
    float acc = xc;
#pragma unroll
    for (int c = 0; c < 32; ++c) {
      uint4 hh = h4[c];
      acc = fdot2u(wv[4 * c + 0], hh.x, acc);
      acc = fdot2u(wv[4 * c + 1], hh.y, acc);
      acc = fdot2u(wv[4 * c + 2], hh.z, acc);
      acc = fdot2u(wv[4 * c + 3], hh.w, acc);
    }
    float act = (gate == 2) ? tanh_f(acc) : sigm(acc);
    gact[j] = act;
    __syncthreads();
    if (j < 64) {
      float iv  = gact[j];
      float fv  = gact[64 + j];
      float gv  = gact[128 + j];
      float ovv = gact[192 + j];
      cst = fv * cst + iv * gv;
      float h = ovv * tanh_f(cst);
      out[(long)t * 512 + dir * 256 + 64 * p + j] = h;
      float hx = __shfl_xor(h, 1);
      if (!(j & 1)) {
        int idx = j >> 1;
        unsigned hp = pack_h2(h, hx);
        h2v[32 * p + idx] = hp;
        u64 tagged = ((u64)(unsigned)(s + 1) << 32) | (u64)hp;
        __hip_atomic_store(&mypay[((s + 1) & 1) * 32 + idx], tagged,
                           __ATOMIC_RELAXED, __HIP_MEMORY_SCOPE_AGENT);
      }
    }
    xc = xn_ + exv;
  }
}

// ---------------- final row softmax ----------------
__global__ __launch_bounds__(256) void softmax_rows(
    const float* __restrict__ logits, float* __restrict__ outp) {
  int t = blockIdx.x, tid = threadIdx.x;
  __shared__ float red[256];
  const float* lr = logits + (long)t * 4096;
  float v[16];
  float mx = -1e30f;
#pragma unroll
  for (int i = 0; i < 16; i++) { v[i] = lr[tid + 256 * i]; mx = fmaxf(mx, v[i]); }
  red[tid] = mx; __syncthreads();
  for (int s = 128; s > 0; s >>= 1) {
    if (tid < s) red[tid] = fmaxf(red[tid], red[tid + s]);
    __syncthreads();
  }
  mx = red[0]; __syncthreads();
  float sm = 0.f;
#pragma unroll
  for (int i = 0; i < 16; i++) { v[i] = __expf(v[i] - mx); sm += v[i]; }
  red[tid] = sm; __syncthreads();
  for (int s = 128; s > 0; s >>= 1) {
    if (tid < s) red[tid] += red[tid + s];
    __syncthreads();
  }
  float rz = 1.f / red[0];
#pragma unroll
  for (int i = 0; i < 16; i++) outp[(long)t * 4096 + tid + 256 * i] = v[i] * rz;
}

// ---------------- launch ----------------
extern "C" void kernel_launch(void* const* d_in, const int* in_sizes, int n_in,
                              void* d_out, int out_size, void* d_ws, size_t ws_size,
                              hipStream_t stream) {
  const float* c        = (const float*)d_in[0];
  const float* memory   = (const float*)d_in[1];
  const float* enc_Wih  = (const float*)d_in[2];
  const float* enc_Whh  = (const float*)d_in[3];
  const float* enc_bih  = (const float*)d_in[4];
  const float* enc_bhh  = (const float*)d_in[5];
  const float* cenc_Wih = (const float*)d_in[6];
  const float* cenc_Whh = (const float*)d_in[7];
  const float* cenc_bih = (const float*)d_in[8];
  const float* cenc_bhh = (const float*)d_in[9];
  const float* know_W   = (const float*)d_in[10];
  const float* know_b   = (const float*)d_in[11];
  const float* l0_Wih   = (const float*)d_in[12];
  const float* l0_Whh   = (const float*)d_in[13];
  const float* l0_bih   = (const float*)d_in[14];
  const float* l0_bhh   = (const float*)d_in[15];
  const float* l1_Wih   = (const float*)d_in[16];
  const float* l1_Whh   = (const float*)d_in[17];
  const float* l1_bih   = (const float*)d_in[18];
  const float* l1_bhh   = (const float*)d_in[19];
  const float* out_W    = (const float*)d_in[20];
  const float* out_b    = (const float*)d_in[21];

  float* ws = (float*)d_ws;
  float* outp = (float*)d_out;

  float* xgg   = ws;                  // 1,572,864   [T][768]
  float* cW    = ws + 1572864;        // 4,194,304   [T][2048]
  float* l0out = ws + 6553600;        // 1,048,576   [T][512]
  float* xg1   = ws + 7602176;        // 4,194,304   [T][2048]
  unsigned* wprep5 = (unsigned*)(ws + 11796480);  // 524,288 u32
  float* bcat  = ws + 12320768;       // 768
  float* bias0 = ws + 12321536;       // 2048
  float* bias1 = ws + 12323584;       // 2048
  float* u_vec = ws + 12325632;       // 256
  float* d_att = ws + 12325888;       // 8192
  float* p_att = ws + 12334080;       // 8192
  float* h_acc = ws + 12342272;       // 256
  float* o_vec = ws + 12342528;       // 1024
  float* ov    = ws + 12343552;       // 2048
  float* l1out = ws + 12345600;       // 1,048,576  (ends 13,394,176)
  unsigned* wgru = (unsigned*)(ws + 13656320);      // 49,152 u32
  u64* payload = (u64*)(ws + 13705472);             // 1024 u64 (ends 13,707,520)
  float* logits = ws;                 // 8,388,608   aliases [0, 8.39M): dead by K11

  // fp16 buffers (aliased where temporally safe):
  _Float16* c16     = (_Float16*)(ws + 12345600);  // in l1out slot: dead before lstm1 writes
  _Float16* wcat16  = (_Float16*)(ws + 7602176);   // in xg1: dead until K9
  _Float16* l0W16   = (_Float16*)(ws + 7995392);   // in xg1: used K2 < K9
  _Float16* l0out16 = (_Float16*)(ws + 1572864);   // in cW: cW dead after lstm0
  _Float16* l1out16 = (_Float16*)(ws + 9043968);   // in xg1: xg1 dead after lstm1; outside logits
  _Float16* l1W16   = (_Float16*)(ws + 13707520);  // NEW: 524,288 floats
  _Float16* outW16  = (_Float16*)(ws + 14231808);  // NEW: 1,048,576 floats (end 15,280,384)

  prep_kernel<<<512, 256, 0, stream>>>(c, enc_Wih, enc_bih, cenc_Wih, cenc_bih,
                                       enc_Whh, cenc_Whh,
                                       l0_Wih, l0_Whh, l1_Wih, l1_Whh, out_W,
                                       l0_bih, l0_bhh, l1_bih, l1_bhh,
                                       bcat, bias0, bias1, wprep5, wgru, payload,
                                       c16, wcat16, l0W16, l1W16, outW16);
  gemm_mfma<<<dim3(12, 32), 256, 0, stream>>>(c16, wcat16, bcat, xgg, 2048, 768, 1024);
  gemm_mfma<<<dim3(32, 32), 256, 0, stream>>>(c16, l0W16, bias0, cW, 2048, 2048, 1024);
  gru2<<<4, 256, 0, stream>>>(xgg, c, wgru, enc_Wih, enc_bih, enc_bhh,
                              cenc_Wih, cenc_bih, cenc_bhh,
                              u_vec, outp + kOUT_ELEMS);
  attn_dots<<<256, 256, 0, stream>>>(memory, u_vec, d_att);
  attn_soft<<<1, 1024, 0, stream>>>(d_att, p_att, h_acc);
  attn_h<<<64, 256, 0, stream>>>(memory, p_att, h_acc);
  attn_o<<<8, 128, 0, stream>>>(u_vec, h_acc, know_W, know_b, o_vec);
  attn_ov<<<16, 128, 0, stream>>>(o_vec, l0_Wih, ov);
  lstm_cc4<<<32, 256, 0, stream>>>(wprep5, cW, ov, l0out, payload);
  cvt16<<<1024, 256, 0, stream>>>(l0out, l0out16, 2048 * 512);
  gemm_mfma<<<dim3(32, 32), 256, 0, stream>>>(l0out16, l1W16, bias1, xg1, 2048, 2048, 512);
  lstm_cc4<<<32, 256, 0, stream>>>(wprep5 + 262144, xg1, nullptr, l1out, payload + 512);
  cvt16<<<1024, 256, 0, stream>>>(l1out, l1out16, 2048 * 512);
  gemm_mfma<<<dim3(64, 32), 256, 0, stream>>>(l1out16, outW16, out_b, logits, 2048, 4096, 512);
  softmax_rows<<<2048, 256, 0, stream>>>(logits, outp);
}